// Round 2
// baseline (1087.780 us; speedup 1.0000x reference)
//
#include <hip/hip_runtime.h>

// H2GCNConv: out[:, 0:64]  = segment_sum(adj1_val * x[adj1_col], adj1_row)
//            out[:, 64:128]= segment_sum(adj2_val * x[adj2_col], adj2_row)
// N=100000, D=64, E1=1.6M, E2=3.2M, fp32.
//
// v2: device-side CSR build (histogram -> scan -> scatter packed (val,col)),
// then one wave per row gathers and writes each output element exactly once.
// Replaces 307M f32 global atomics (1.2GB fabric write-through, the v1
// bottleneck) with 9.6M int atomics + 38MB sorted-edge traffic.

#define NFEAT 64
#define OUT_STRIDE 128

// ---------------- phase 1: per-row edge counts ----------------
__global__ __launch_bounds__(256) void hist_kernel(
    const int* __restrict__ r1, int e1,
    const int* __restrict__ r2, int e2,
    int* __restrict__ c1, int* __restrict__ c2) {
  const int tid = blockIdx.x * blockDim.x + threadIdx.x;
  const int stride = gridDim.x * blockDim.x;
  for (int k = tid; k < e1; k += stride) atomicAdd(&c1[r1[k]], 1);
  for (int k = tid; k < e2; k += stride) atomicAdd(&c2[r2[k]], 1);
}

// ---------------- phase 2: exclusive scan (2 blocks, one per adjacency) ----
__device__ __forceinline__ int wave_incl_scan(int v) {
#pragma unroll
  for (int ofs = 1; ofs < 64; ofs <<= 1) {
    int u = __shfl_up(v, ofs, 64);
    if ((int)(threadIdx.x & 63) >= ofs) v += u;
  }
  return v;
}

// Scans cnt -> off (exclusive, plus total at off[n]); ALSO rewrites cnt[i] to
// the exclusive prefix so cnt doubles as the scatter cursor array.
__global__ __launch_bounds__(1024) void scan_kernel(
    int* __restrict__ cnt1, int* __restrict__ off1,
    int* __restrict__ cnt2, int* __restrict__ off2, int n) {
  int* cnt = (blockIdx.x == 0) ? cnt1 : cnt2;
  int* off = (blockIdx.x == 0) ? off1 : off2;
  __shared__ int wsum[16];
  __shared__ int wbase[16];
  __shared__ int sbase;
  const int t = threadIdx.x, lane = t & 63, wid = t >> 6;
  if (t == 0) sbase = 0;
  __syncthreads();
  for (int start = 0; start < n; start += 4096) {
    const int idx = start + t * 4;
    int v[4];
#pragma unroll
    for (int j = 0; j < 4; ++j) v[j] = (idx + j < n) ? cnt[idx + j] : 0;
    const int local = v[0] + v[1] + v[2] + v[3];
    const int incl = wave_incl_scan(local);
    if (lane == 63) wsum[wid] = incl;
    __syncthreads();
    if (wid == 0) {
      int s = (lane < 16) ? wsum[lane] : 0;
      int si = wave_incl_scan(s);
      if (lane < 16) wbase[lane] = si - s;  // exclusive wave base
    }
    __syncthreads();
    int run = sbase + wbase[wid] + (incl - local);  // thread's exclusive prefix
#pragma unroll
    for (int j = 0; j < 4; ++j) {
      if (idx + j < n) { off[idx + j] = run; cnt[idx + j] = run; }
      run += v[j];
    }
    __syncthreads();
    if (t == 1023) sbase = run;  // chunk-inclusive total
    __syncthreads();
  }
  if (t == 0) off[n] = sbase;
}

// ---------------- phase 3: scatter edges into row-sorted packed records ----
__global__ __launch_bounds__(256) void scatter_kernel(
    const int* __restrict__ r1, const int* __restrict__ c1, const float* __restrict__ v1, int e1,
    const int* __restrict__ r2, const int* __restrict__ c2, const float* __restrict__ v2, int e2,
    int* __restrict__ cur1, int* __restrict__ cur2,
    long long* __restrict__ p1, long long* __restrict__ p2) {
  const int tid = blockIdx.x * blockDim.x + threadIdx.x;
  const int stride = gridDim.x * blockDim.x;
  for (int k = tid; k < e1; k += stride) {
    int pos = atomicAdd(&cur1[r1[k]], 1);
    p1[pos] = ((long long)(unsigned long long)__float_as_uint(v1[k]) << 32) |
              (unsigned)c1[k];
  }
  for (int k = tid; k < e2; k += stride) {
    int pos = atomicAdd(&cur2[r2[k]], 1);
    p2[pos] = ((long long)(unsigned long long)__float_as_uint(v2[k]) << 32) |
              (unsigned)c2[k];
  }
}

// ---------------- phase 4: per-row gather, write once --------------------
__global__ __launch_bounds__(256) void gather_kernel(
    const int* __restrict__ off1, const long long* __restrict__ p1,
    const int* __restrict__ off2, const long long* __restrict__ p2,
    const float* __restrict__ x, float* __restrict__ out, int n) {
  const int lane = threadIdx.x & 63;
  const int r = (blockIdx.x * blockDim.x + threadIdx.x) >> 6;
  if (r >= n) return;

  int s = off1[r], e = off1[r + 1];
  float acc = 0.f;
  for (int k = s; k < e; ++k) {
    long long pk = p1[k];
    int col = (int)((unsigned long long)pk & 0xffffffffull);
    float val = __uint_as_float((unsigned)((unsigned long long)pk >> 32));
    acc = fmaf(val, x[(long)col * NFEAT + lane], acc);
  }
  out[(long)r * OUT_STRIDE + lane] = acc;

  s = off2[r]; e = off2[r + 1];
  acc = 0.f;
  for (int k = s; k < e; ++k) {
    long long pk = p2[k];
    int col = (int)((unsigned long long)pk & 0xffffffffull);
    float val = __uint_as_float((unsigned)((unsigned long long)pk >> 32));
    acc = fmaf(val, x[(long)col * NFEAT + lane], acc);
  }
  out[(long)r * OUT_STRIDE + NFEAT + lane] = acc;
}

// ---------------- fallback (v1): atomic scatter ---------------------------
__global__ __launch_bounds__(256) void spmm_scatter_kernel(
    const int* __restrict__ row, const int* __restrict__ col,
    const float* __restrict__ val, const float* __restrict__ x,
    float* __restrict__ out, int nedges, int col_off) {
  const int lane = threadIdx.x & 63;
  const int wid = (blockIdx.x * blockDim.x + threadIdx.x) >> 6;
  const int nwaves = (gridDim.x * blockDim.x) >> 6;
  for (int e = wid; e < nedges; e += nwaves) {
    const int r = row[e];
    const int c = col[e];
    const float v = val[e];
    const float xv = x[(long)c * NFEAT + lane];
    atomicAdd(&out[(long)r * OUT_STRIDE + col_off + lane], v * xv);
  }
}

extern "C" void kernel_launch(void* const* d_in, const int* in_sizes, int n_in,
                              void* d_out, int out_size, void* d_ws, size_t ws_size,
                              hipStream_t stream) {
  const float* x        = (const float*)d_in[0];
  const int*   adj1_row = (const int*)d_in[1];
  const int*   adj1_col = (const int*)d_in[2];
  const float* adj1_val = (const float*)d_in[3];
  const int*   adj2_row = (const int*)d_in[4];
  const int*   adj2_col = (const int*)d_in[5];
  const float* adj2_val = (const float*)d_in[6];

  const int e1 = in_sizes[1];
  const int e2 = in_sizes[4];
  const int n  = in_sizes[0] / NFEAT;  // 100000

  float* out = (float*)d_out;

  // Workspace layout (8B-aligned first):
  //   p1[e1] (8B), p2[e2] (8B), off1[n+1], off2[n+1], cnt1[n], cnt2[n]
  const size_t need = (size_t)(e1 + e2) * 8 + 2 * (size_t)(n + 1) * 4 +
                      2 * (size_t)n * 4;
  if (ws_size < need) {
    // Fallback: v1 atomic path.
    hipMemsetAsync(d_out, 0, (size_t)out_size * sizeof(float), stream);
    spmm_scatter_kernel<<<4096, 256, 0, stream>>>(adj1_row, adj1_col, adj1_val,
                                                  x, out, e1, 0);
    spmm_scatter_kernel<<<4096, 256, 0, stream>>>(adj2_row, adj2_col, adj2_val,
                                                  x, out, e2, NFEAT);
    return;
  }

  char* w = (char*)d_ws;
  long long* p1 = (long long*)w;  w += (size_t)e1 * 8;
  long long* p2 = (long long*)w;  w += (size_t)e2 * 8;
  int* off1 = (int*)w;            w += (size_t)(n + 1) * 4;
  int* off2 = (int*)w;            w += (size_t)(n + 1) * 4;
  int* cnt1 = (int*)w;            w += (size_t)n * 4;
  int* cnt2 = (int*)w;            // contiguous with cnt1

  // counts -> 0 (cnt arrays are contiguous: one memset)
  hipMemsetAsync(cnt1, 0, 2 * (size_t)n * 4, stream);

  hist_kernel<<<2048, 256, 0, stream>>>(adj1_row, e1, adj2_row, e2, cnt1, cnt2);
  scan_kernel<<<2, 1024, 0, stream>>>(cnt1, off1, cnt2, off2, n);
  scatter_kernel<<<2048, 256, 0, stream>>>(adj1_row, adj1_col, adj1_val, e1,
                                           adj2_row, adj2_col, adj2_val, e2,
                                           cnt1, cnt2, p1, p2);
  // One wave per row; writes every output element exactly once (no memset).
  gather_kernel<<<(n * 64 + 255) / 256, 256, 0, stream>>>(off1, p1, off2, p2,
                                                          x, out, n);
}

// Round 3
// 790.233 us; speedup vs baseline: 1.3765x; 1.3765x over previous
//
#include <hip/hip_runtime.h>

// H2GCNConv: out[:, 0:64]  = segment_sum(adj1_val * x[adj1_col], adj1_row)
//            out[:, 64:128]= segment_sum(adj2_val * x[adj2_col], adj2_row)
// N=100000, D=64, E1=1.6M, E2=3.2M, fp32.
//
// v3: CSR pipeline, all phases tuned.
//  p1_hist      : int4-vectorized row reads, int atomics into counts
//  p2a/p2b/p2c  : parallel 3-kernel exclusive scan (1024 elems/block)
//  p3_scatter   : 4 edges/thread, packed (val,col) 8B records, NT stores
//  p4_gather    : one wave per (row, half), edge loop unrolled x4 so each
//                 wave keeps 4 independent x-row gathers in flight
//                 (v2 gather was a serial dependent chain: 1.46 TB/s, 14% VALU)

#define NFEAT 64
#define OUT_STRIDE 128
#define SCAN_BLK 1024  // elements per scan block

__device__ __forceinline__ int wave_incl_scan(int v) {
#pragma unroll
  for (int ofs = 1; ofs < 64; ofs <<= 1) {
    int u = __shfl_up(v, ofs, 64);
    if ((int)(threadIdx.x & 63) >= ofs) v += u;
  }
  return v;
}

// ---------------- phase 1: per-row edge counts ----------------
__global__ __launch_bounds__(256) void p1_hist(
    const int* __restrict__ r1, int e1,
    const int* __restrict__ r2, int e2,
    int* __restrict__ c1, int* __restrict__ c2) {
  const int tid = blockIdx.x * blockDim.x + threadIdx.x;
  const int stride = gridDim.x * blockDim.x;

  const int e1v = e1 >> 2;
  const int4* r1v = (const int4*)r1;
  for (int k = tid; k < e1v; k += stride) {
    int4 q = r1v[k];
    atomicAdd(&c1[q.x], 1); atomicAdd(&c1[q.y], 1);
    atomicAdd(&c1[q.z], 1); atomicAdd(&c1[q.w], 1);
  }
  for (int k = (e1v << 2) + tid; k < e1; k += stride) atomicAdd(&c1[r1[k]], 1);

  const int e2v = e2 >> 2;
  const int4* r2v = (const int4*)r2;
  for (int k = tid; k < e2v; k += stride) {
    int4 q = r2v[k];
    atomicAdd(&c2[q.x], 1); atomicAdd(&c2[q.y], 1);
    atomicAdd(&c2[q.z], 1); atomicAdd(&c2[q.w], 1);
  }
  for (int k = (e2v << 2) + tid; k < e2; k += stride) atomicAdd(&c2[r2[k]], 1);
}

// ---------------- phase 2a: per-block sums ----------------
__global__ __launch_bounds__(256) void p2a_blocksum(
    const int* __restrict__ cnt1, const int* __restrict__ cnt2,
    int n, int nb, int* __restrict__ bsum) {
  const int b = blockIdx.x;                 // 0..2nb-1
  const int seg = (b < nb) ? 0 : 1;
  const int* cnt = seg ? cnt2 : cnt1;
  const int blk = seg ? (b - nb) : b;
  const int t = threadIdx.x, lane = t & 63, wid = t >> 6;
  const int i0 = blk * SCAN_BLK + t * 4;
  int s = 0;
#pragma unroll
  for (int j = 0; j < 4; ++j) s += (i0 + j < n) ? cnt[i0 + j] : 0;
#pragma unroll
  for (int ofs = 32; ofs > 0; ofs >>= 1) s += __shfl_down(s, ofs, 64);
  __shared__ int ws[4];
  if (lane == 0) ws[wid] = s;
  __syncthreads();
  if (t == 0) bsum[b] = ws[0] + ws[1] + ws[2] + ws[3];
}

// ---------------- phase 2b: scan the block sums (1 block) ----------------
__global__ __launch_bounds__(256) void p2b_scanb(
    int* __restrict__ bsum, int nb,
    int* __restrict__ off1, int* __restrict__ off2, int n) {
  __shared__ int sh[256];
  const int t = threadIdx.x;
  for (int seg = 0; seg < 2; ++seg) {
    int v = (t < nb) ? bsum[seg * nb + t] : 0;
    sh[t] = v;
    __syncthreads();
    for (int ofs = 1; ofs < 256; ofs <<= 1) {
      int u = (t >= ofs) ? sh[t - ofs] : 0;
      __syncthreads();
      sh[t] += u;
      __syncthreads();
    }
    if (t < nb) bsum[seg * nb + t] = sh[t] - v;  // exclusive block base
    if (t == 255) {
      int* offp = seg ? off2 : off1;
      offp[n] = sh[255];  // segment total
    }
    __syncthreads();
  }
}

// ---------------- phase 2c: apply bases; cnt becomes the scatter cursor ----
__global__ __launch_bounds__(256) void p2c_apply(
    int* __restrict__ cnt1, int* __restrict__ cnt2, int n, int nb,
    const int* __restrict__ bsum,
    int* __restrict__ off1, int* __restrict__ off2) {
  const int b = blockIdx.x;
  const int seg = (b < nb) ? 0 : 1;
  int* cnt = seg ? cnt2 : cnt1;
  int* off = seg ? off2 : off1;
  const int blk = seg ? (b - nb) : b;
  const int t = threadIdx.x, lane = t & 63, wid = t >> 6;
  const int i0 = blk * SCAN_BLK + t * 4;

  int v[4];
#pragma unroll
  for (int j = 0; j < 4; ++j) v[j] = (i0 + j < n) ? cnt[i0 + j] : 0;
  const int local = v[0] + v[1] + v[2] + v[3];
  const int incl = wave_incl_scan(local);

  __shared__ int ws[4];
  if (lane == 63) ws[wid] = incl;
  __syncthreads();
  int wbase = 0;
#pragma unroll
  for (int w = 0; w < 4; ++w) wbase += (w < wid) ? ws[w] : 0;

  int run = bsum[b] + wbase + (incl - local);
#pragma unroll
  for (int j = 0; j < 4; ++j) {
    if (i0 + j < n) { off[i0 + j] = run; cnt[i0 + j] = run; }
    run += v[j];
  }
}

// ---------------- phase 3: scatter into row-sorted packed records ----------
__device__ __forceinline__ long long pack_rec(float v, int c) {
  return ((long long)(unsigned long long)__float_as_uint(v) << 32) |
         (unsigned)c;
}

__global__ __launch_bounds__(256) void p3_scatter(
    const int* __restrict__ r1, const int* __restrict__ c1,
    const float* __restrict__ v1, int e1,
    const int* __restrict__ r2, const int* __restrict__ c2,
    const float* __restrict__ v2, int e2,
    int* __restrict__ cur1, int* __restrict__ cur2,
    long long* __restrict__ p1, long long* __restrict__ p2) {
  const int tid = blockIdx.x * blockDim.x + threadIdx.x;
  const int stride = gridDim.x * blockDim.x;

  const int e1v = e1 >> 2;
  const int4* r1q = (const int4*)r1;
  const int4* c1q = (const int4*)c1;
  const float4* v1q = (const float4*)v1;
  for (int k = tid; k < e1v; k += stride) {
    int4 r = r1q[k]; int4 c = c1q[k]; float4 v = v1q[k];
    int q0 = atomicAdd(&cur1[r.x], 1);
    int q1 = atomicAdd(&cur1[r.y], 1);
    int q2 = atomicAdd(&cur1[r.z], 1);
    int q3 = atomicAdd(&cur1[r.w], 1);
    __builtin_nontemporal_store(pack_rec(v.x, c.x), &p1[q0]);
    __builtin_nontemporal_store(pack_rec(v.y, c.y), &p1[q1]);
    __builtin_nontemporal_store(pack_rec(v.z, c.z), &p1[q2]);
    __builtin_nontemporal_store(pack_rec(v.w, c.w), &p1[q3]);
  }
  for (int k = (e1v << 2) + tid; k < e1; k += stride) {
    int pos = atomicAdd(&cur1[r1[k]], 1);
    __builtin_nontemporal_store(pack_rec(v1[k], c1[k]), &p1[pos]);
  }

  const int e2v = e2 >> 2;
  const int4* r2q = (const int4*)r2;
  const int4* c2q = (const int4*)c2;
  const float4* v2q = (const float4*)v2;
  for (int k = tid; k < e2v; k += stride) {
    int4 r = r2q[k]; int4 c = c2q[k]; float4 v = v2q[k];
    int q0 = atomicAdd(&cur2[r.x], 1);
    int q1 = atomicAdd(&cur2[r.y], 1);
    int q2 = atomicAdd(&cur2[r.z], 1);
    int q3 = atomicAdd(&cur2[r.w], 1);
    __builtin_nontemporal_store(pack_rec(v.x, c.x), &p2[q0]);
    __builtin_nontemporal_store(pack_rec(v.y, c.y), &p2[q1]);
    __builtin_nontemporal_store(pack_rec(v.z, c.z), &p2[q2]);
    __builtin_nontemporal_store(pack_rec(v.w, c.w), &p2[q3]);
  }
  for (int k = (e2v << 2) + tid; k < e2; k += stride) {
    int pos = atomicAdd(&cur2[r2[k]], 1);
    __builtin_nontemporal_store(pack_rec(v2[k], c2[k]), &p2[pos]);
  }
}

// ---------------- phase 4: gather, one wave per (row, half) ---------------
__global__ __launch_bounds__(256) void p4_gather(
    const int* __restrict__ off1, const long long* __restrict__ p1,
    const int* __restrict__ off2, const long long* __restrict__ p2,
    const float* __restrict__ x, float* __restrict__ out, int n) {
  const int lane = threadIdx.x & 63;
  const int w = (blockIdx.x * blockDim.x + threadIdx.x) >> 6;
  if (w >= 2 * n) return;
  const int half = (w >= n) ? 1 : 0;
  const int r = half ? (w - n) : w;
  const int* off = half ? off2 : off1;
  const long long* pp = half ? p2 : p1;

  const int s = off[r], e = off[r + 1];
  float acc = 0.f;
  int k = s;
  // 4 independent x-row gathers in flight per iteration.
  for (; k + 4 <= e; k += 4) {
    long long q0 = pp[k], q1 = pp[k + 1], q2 = pp[k + 2], q3 = pp[k + 3];
    int c0 = (int)((unsigned long long)q0 & 0xffffffffull);
    int c1 = (int)((unsigned long long)q1 & 0xffffffffull);
    int c2 = (int)((unsigned long long)q2 & 0xffffffffull);
    int c3 = (int)((unsigned long long)q3 & 0xffffffffull);
    float f0 = __uint_as_float((unsigned)((unsigned long long)q0 >> 32));
    float f1 = __uint_as_float((unsigned)((unsigned long long)q1 >> 32));
    float f2 = __uint_as_float((unsigned)((unsigned long long)q2 >> 32));
    float f3 = __uint_as_float((unsigned)((unsigned long long)q3 >> 32));
    float x0 = x[(long)c0 * NFEAT + lane];
    float x1 = x[(long)c1 * NFEAT + lane];
    float x2 = x[(long)c2 * NFEAT + lane];
    float x3 = x[(long)c3 * NFEAT + lane];
    acc = fmaf(f0, x0, acc);
    acc = fmaf(f1, x1, acc);
    acc = fmaf(f2, x2, acc);
    acc = fmaf(f3, x3, acc);
  }
  for (; k < e; ++k) {
    long long q = pp[k];
    int c = (int)((unsigned long long)q & 0xffffffffull);
    float f = __uint_as_float((unsigned)((unsigned long long)q >> 32));
    acc = fmaf(f, x[(long)c * NFEAT + lane], acc);
  }
  out[(long)r * OUT_STRIDE + half * NFEAT + lane] = acc;
}

// ---------------- fallback (v1): atomic scatter ---------------------------
__global__ __launch_bounds__(256) void spmm_scatter_kernel(
    const int* __restrict__ row, const int* __restrict__ col,
    const float* __restrict__ val, const float* __restrict__ x,
    float* __restrict__ out, int nedges, int col_off) {
  const int lane = threadIdx.x & 63;
  const int wid = (blockIdx.x * blockDim.x + threadIdx.x) >> 6;
  const int nwaves = (gridDim.x * blockDim.x) >> 6;
  for (int e = wid; e < nedges; e += nwaves) {
    const int r = row[e];
    const int c = col[e];
    const float v = val[e];
    const float xv = x[(long)c * NFEAT + lane];
    atomicAdd(&out[(long)r * OUT_STRIDE + col_off + lane], v * xv);
  }
}

extern "C" void kernel_launch(void* const* d_in, const int* in_sizes, int n_in,
                              void* d_out, int out_size, void* d_ws, size_t ws_size,
                              hipStream_t stream) {
  const float* x        = (const float*)d_in[0];
  const int*   adj1_row = (const int*)d_in[1];
  const int*   adj1_col = (const int*)d_in[2];
  const float* adj1_val = (const float*)d_in[3];
  const int*   adj2_row = (const int*)d_in[4];
  const int*   adj2_col = (const int*)d_in[5];
  const float* adj2_val = (const float*)d_in[6];

  const int e1 = in_sizes[1];
  const int e2 = in_sizes[4];
  const int n  = in_sizes[0] / NFEAT;  // 100000
  const int nb = (n + SCAN_BLK - 1) / SCAN_BLK;  // 98

  float* out = (float*)d_out;

  // Workspace: p1[e1](8B), p2[e2](8B), off1[n+1], off2[n+1], cnt1[n], cnt2[n],
  //            bsum[2*nb]
  const size_t need = (size_t)(e1 + e2) * 8 + 2 * (size_t)(n + 1) * 4 +
                      2 * (size_t)n * 4 + 2 * (size_t)nb * 4;
  if (ws_size < need || nb > 256) {
    hipMemsetAsync(d_out, 0, (size_t)out_size * sizeof(float), stream);
    spmm_scatter_kernel<<<4096, 256, 0, stream>>>(adj1_row, adj1_col, adj1_val,
                                                  x, out, e1, 0);
    spmm_scatter_kernel<<<4096, 256, 0, stream>>>(adj2_row, adj2_col, adj2_val,
                                                  x, out, e2, NFEAT);
    return;
  }

  char* w = (char*)d_ws;
  long long* p1 = (long long*)w;  w += (size_t)e1 * 8;
  long long* p2 = (long long*)w;  w += (size_t)e2 * 8;
  int* off1 = (int*)w;            w += (size_t)(n + 1) * 4;
  int* off2 = (int*)w;            w += (size_t)(n + 1) * 4;
  int* cnt1 = (int*)w;            w += (size_t)n * 4;
  int* cnt2 = (int*)w;            w += (size_t)n * 4;
  int* bsum = (int*)w;

  hipMemsetAsync(cnt1, 0, 2 * (size_t)n * 4, stream);

  p1_hist<<<2048, 256, 0, stream>>>(adj1_row, e1, adj2_row, e2, cnt1, cnt2);
  p2a_blocksum<<<2 * nb, 256, 0, stream>>>(cnt1, cnt2, n, nb, bsum);
  p2b_scanb<<<1, 256, 0, stream>>>(bsum, nb, off1, off2, n);
  p2c_apply<<<2 * nb, 256, 0, stream>>>(cnt1, cnt2, n, nb, bsum, off1, off2);
  p3_scatter<<<2048, 256, 0, stream>>>(adj1_row, adj1_col, adj1_val, e1,
                                       adj2_row, adj2_col, adj2_val, e2,
                                       cnt1, cnt2, p1, p2);
  p4_gather<<<(2 * n * 64 + 255) / 256, 256, 0, stream>>>(off1, p1, off2, p2,
                                                          x, out, n);
}

// Round 4
// 714.515 us; speedup vs baseline: 1.5224x; 1.1060x over previous
//
#include <hip/hip_runtime.h>

// H2GCNConv: out[:, 0:64]  = segment_sum(adj1_val * x[adj1_col], adj1_row)
//            out[:, 64:128]= segment_sum(adj2_val * x[adj2_col], adj2_row)
// N=100000, D=64, E1=1.6M, E2=3.2M, fp32.
//
// v4: CSR pipeline.
//  - p3_scatter now uses PLAIN stores. v3's nontemporal stores forced each
//    random 8B record to evict its own partial 64B line (WRITE_SIZE was
//    exactly 64B/record = 298MB). Cursor positions are allocated in arrival
//    order, so same-row records written close in time share an L2 line and
//    merge -- but only if the line isn't NT-evicted.
//  - p4_gather unrolled x8 (long2 record loads, dual accumulators) to keep
//    8 independent x-row gathers in flight per wave.

#define NFEAT 64
#define OUT_STRIDE 128
#define SCAN_BLK 1024  // elements per scan block

__device__ __forceinline__ int wave_incl_scan(int v) {
#pragma unroll
  for (int ofs = 1; ofs < 64; ofs <<= 1) {
    int u = __shfl_up(v, ofs, 64);
    if ((int)(threadIdx.x & 63) >= ofs) v += u;
  }
  return v;
}

// ---------------- phase 1: per-row edge counts ----------------
__global__ __launch_bounds__(256) void p1_hist(
    const int* __restrict__ r1, int e1,
    const int* __restrict__ r2, int e2,
    int* __restrict__ c1, int* __restrict__ c2) {
  const int tid = blockIdx.x * blockDim.x + threadIdx.x;
  const int stride = gridDim.x * blockDim.x;

  const int e1v = e1 >> 2;
  const int4* r1v = (const int4*)r1;
  for (int k = tid; k < e1v; k += stride) {
    int4 q = r1v[k];
    atomicAdd(&c1[q.x], 1); atomicAdd(&c1[q.y], 1);
    atomicAdd(&c1[q.z], 1); atomicAdd(&c1[q.w], 1);
  }
  for (int k = (e1v << 2) + tid; k < e1; k += stride) atomicAdd(&c1[r1[k]], 1);

  const int e2v = e2 >> 2;
  const int4* r2v = (const int4*)r2;
  for (int k = tid; k < e2v; k += stride) {
    int4 q = r2v[k];
    atomicAdd(&c2[q.x], 1); atomicAdd(&c2[q.y], 1);
    atomicAdd(&c2[q.z], 1); atomicAdd(&c2[q.w], 1);
  }
  for (int k = (e2v << 2) + tid; k < e2; k += stride) atomicAdd(&c2[r2[k]], 1);
}

// ---------------- phase 2a: per-block sums ----------------
__global__ __launch_bounds__(256) void p2a_blocksum(
    const int* __restrict__ cnt1, const int* __restrict__ cnt2,
    int n, int nb, int* __restrict__ bsum) {
  const int b = blockIdx.x;                 // 0..2nb-1
  const int seg = (b < nb) ? 0 : 1;
  const int* cnt = seg ? cnt2 : cnt1;
  const int blk = seg ? (b - nb) : b;
  const int t = threadIdx.x, lane = t & 63, wid = t >> 6;
  const int i0 = blk * SCAN_BLK + t * 4;
  int s = 0;
#pragma unroll
  for (int j = 0; j < 4; ++j) s += (i0 + j < n) ? cnt[i0 + j] : 0;
#pragma unroll
  for (int ofs = 32; ofs > 0; ofs >>= 1) s += __shfl_down(s, ofs, 64);
  __shared__ int ws[4];
  if (lane == 0) ws[wid] = s;
  __syncthreads();
  if (t == 0) bsum[b] = ws[0] + ws[1] + ws[2] + ws[3];
}

// ---------------- phase 2b: scan the block sums (1 block) ----------------
__global__ __launch_bounds__(256) void p2b_scanb(
    int* __restrict__ bsum, int nb,
    int* __restrict__ off1, int* __restrict__ off2, int n) {
  __shared__ int sh[256];
  const int t = threadIdx.x;
  for (int seg = 0; seg < 2; ++seg) {
    int v = (t < nb) ? bsum[seg * nb + t] : 0;
    sh[t] = v;
    __syncthreads();
    for (int ofs = 1; ofs < 256; ofs <<= 1) {
      int u = (t >= ofs) ? sh[t - ofs] : 0;
      __syncthreads();
      sh[t] += u;
      __syncthreads();
    }
    if (t < nb) bsum[seg * nb + t] = sh[t] - v;  // exclusive block base
    if (t == 255) {
      int* offp = seg ? off2 : off1;
      offp[n] = sh[255];  // segment total
    }
    __syncthreads();
  }
}

// ---------------- phase 2c: apply bases; cnt becomes the scatter cursor ----
__global__ __launch_bounds__(256) void p2c_apply(
    int* __restrict__ cnt1, int* __restrict__ cnt2, int n, int nb,
    const int* __restrict__ bsum,
    int* __restrict__ off1, int* __restrict__ off2) {
  const int b = blockIdx.x;
  const int seg = (b < nb) ? 0 : 1;
  int* cnt = seg ? cnt2 : cnt1;
  int* off = seg ? off2 : off1;
  const int blk = seg ? (b - nb) : b;
  const int t = threadIdx.x, lane = t & 63, wid = t >> 6;
  const int i0 = blk * SCAN_BLK + t * 4;

  int v[4];
#pragma unroll
  for (int j = 0; j < 4; ++j) v[j] = (i0 + j < n) ? cnt[i0 + j] : 0;
  const int local = v[0] + v[1] + v[2] + v[3];
  const int incl = wave_incl_scan(local);

  __shared__ int ws[4];
  if (lane == 63) ws[wid] = incl;
  __syncthreads();
  int wbase = 0;
#pragma unroll
  for (int w = 0; w < 4; ++w) wbase += (w < wid) ? ws[w] : 0;

  int run = bsum[b] + wbase + (incl - local);
#pragma unroll
  for (int j = 0; j < 4; ++j) {
    if (i0 + j < n) { off[i0 + j] = run; cnt[i0 + j] = run; }
    run += v[j];
  }
}

// ---------------- phase 3: scatter into row-sorted packed records ----------
__device__ __forceinline__ long long pack_rec(float v, int c) {
  return ((long long)(unsigned long long)__float_as_uint(v) << 32) |
         (unsigned)c;
}

__global__ __launch_bounds__(256) void p3_scatter(
    const int* __restrict__ r1, const int* __restrict__ c1,
    const float* __restrict__ v1, int e1,
    const int* __restrict__ r2, const int* __restrict__ c2,
    const float* __restrict__ v2, int e2,
    int* __restrict__ cur1, int* __restrict__ cur2,
    long long* __restrict__ p1, long long* __restrict__ p2) {
  const int tid = blockIdx.x * blockDim.x + threadIdx.x;
  const int stride = gridDim.x * blockDim.x;

  const int e1v = e1 >> 2;
  const int4* r1q = (const int4*)r1;
  const int4* c1q = (const int4*)c1;
  const float4* v1q = (const float4*)v1;
  for (int k = tid; k < e1v; k += stride) {
    int4 r = r1q[k]; int4 c = c1q[k]; float4 v = v1q[k];
    int q0 = atomicAdd(&cur1[r.x], 1);
    int q1 = atomicAdd(&cur1[r.y], 1);
    int q2 = atomicAdd(&cur1[r.z], 1);
    int q3 = atomicAdd(&cur1[r.w], 1);
    p1[q0] = pack_rec(v.x, c.x);
    p1[q1] = pack_rec(v.y, c.y);
    p1[q2] = pack_rec(v.z, c.z);
    p1[q3] = pack_rec(v.w, c.w);
  }
  for (int k = (e1v << 2) + tid; k < e1; k += stride) {
    int pos = atomicAdd(&cur1[r1[k]], 1);
    p1[pos] = pack_rec(v1[k], c1[k]);
  }

  const int e2v = e2 >> 2;
  const int4* r2q = (const int4*)r2;
  const int4* c2q = (const int4*)c2;
  const float4* v2q = (const float4*)v2;
  for (int k = tid; k < e2v; k += stride) {
    int4 r = r2q[k]; int4 c = c2q[k]; float4 v = v2q[k];
    int q0 = atomicAdd(&cur2[r.x], 1);
    int q1 = atomicAdd(&cur2[r.y], 1);
    int q2 = atomicAdd(&cur2[r.z], 1);
    int q3 = atomicAdd(&cur2[r.w], 1);
    p2[q0] = pack_rec(v.x, c.x);
    p2[q1] = pack_rec(v.y, c.y);
    p2[q2] = pack_rec(v.z, c.z);
    p2[q3] = pack_rec(v.w, c.w);
  }
  for (int k = (e2v << 2) + tid; k < e2; k += stride) {
    int pos = atomicAdd(&cur2[r2[k]], 1);
    p2[pos] = pack_rec(v2[k], c2[k]);
  }
}

// ---------------- phase 4: gather, one wave per (row, half), ILP=8 --------
__device__ __forceinline__ void rec2(const long long q, int& c, float& f) {
  c = (int)((unsigned long long)q & 0xffffffffull);
  f = __uint_as_float((unsigned)((unsigned long long)q >> 32));
}

__global__ __launch_bounds__(256) void p4_gather(
    const int* __restrict__ off1, const long long* __restrict__ p1,
    const int* __restrict__ off2, const long long* __restrict__ p2,
    const float* __restrict__ x, float* __restrict__ out, int n) {
  const int lane = threadIdx.x & 63;
  const int w = (blockIdx.x * blockDim.x + threadIdx.x) >> 6;
  if (w >= 2 * n) return;
  const int half = (w >= n) ? 1 : 0;
  const int r = half ? (w - n) : w;
  const int* off = half ? off2 : off1;
  const long long* pp = half ? p2 : p1;

  const int s = off[r], e = off[r + 1];
  float acc0 = 0.f, acc1 = 0.f;
  int k = s;
  // 8 independent x-row gathers in flight per iteration.
  for (; k + 8 <= e; k += 8) {
    long long q0 = pp[k + 0], q1 = pp[k + 1], q2 = pp[k + 2], q3 = pp[k + 3];
    long long q4 = pp[k + 4], q5 = pp[k + 5], q6 = pp[k + 6], q7 = pp[k + 7];
    int c0, c1, c2, c3, c4, c5, c6, c7;
    float f0, f1, f2, f3, f4, f5, f6, f7;
    rec2(q0, c0, f0); rec2(q1, c1, f1); rec2(q2, c2, f2); rec2(q3, c3, f3);
    rec2(q4, c4, f4); rec2(q5, c5, f5); rec2(q6, c6, f6); rec2(q7, c7, f7);
    float x0 = x[(long)c0 * NFEAT + lane];
    float x1 = x[(long)c1 * NFEAT + lane];
    float x2 = x[(long)c2 * NFEAT + lane];
    float x3 = x[(long)c3 * NFEAT + lane];
    float x4 = x[(long)c4 * NFEAT + lane];
    float x5 = x[(long)c5 * NFEAT + lane];
    float x6 = x[(long)c6 * NFEAT + lane];
    float x7 = x[(long)c7 * NFEAT + lane];
    acc0 = fmaf(f0, x0, acc0); acc1 = fmaf(f1, x1, acc1);
    acc0 = fmaf(f2, x2, acc0); acc1 = fmaf(f3, x3, acc1);
    acc0 = fmaf(f4, x4, acc0); acc1 = fmaf(f5, x5, acc1);
    acc0 = fmaf(f6, x6, acc0); acc1 = fmaf(f7, x7, acc1);
  }
  if (k + 4 <= e) {
    long long q0 = pp[k + 0], q1 = pp[k + 1], q2 = pp[k + 2], q3 = pp[k + 3];
    int c0, c1, c2, c3;
    float f0, f1, f2, f3;
    rec2(q0, c0, f0); rec2(q1, c1, f1); rec2(q2, c2, f2); rec2(q3, c3, f3);
    float x0 = x[(long)c0 * NFEAT + lane];
    float x1 = x[(long)c1 * NFEAT + lane];
    float x2 = x[(long)c2 * NFEAT + lane];
    float x3 = x[(long)c3 * NFEAT + lane];
    acc0 = fmaf(f0, x0, acc0); acc1 = fmaf(f1, x1, acc1);
    acc0 = fmaf(f2, x2, acc0); acc1 = fmaf(f3, x3, acc1);
    k += 4;
  }
  for (; k < e; ++k) {
    int c; float f;
    rec2(pp[k], c, f);
    acc0 = fmaf(f, x[(long)c * NFEAT + lane], acc0);
  }
  out[(long)r * OUT_STRIDE + half * NFEAT + lane] = acc0 + acc1;
}

// ---------------- fallback (v1): atomic scatter ---------------------------
__global__ __launch_bounds__(256) void spmm_scatter_kernel(
    const int* __restrict__ row, const int* __restrict__ col,
    const float* __restrict__ val, const float* __restrict__ x,
    float* __restrict__ out, int nedges, int col_off) {
  const int lane = threadIdx.x & 63;
  const int wid = (blockIdx.x * blockDim.x + threadIdx.x) >> 6;
  const int nwaves = (gridDim.x * blockDim.x) >> 6;
  for (int e = wid; e < nedges; e += nwaves) {
    const int r = row[e];
    const int c = col[e];
    const float v = val[e];
    const float xv = x[(long)c * NFEAT + lane];
    atomicAdd(&out[(long)r * OUT_STRIDE + col_off + lane], v * xv);
  }
}

extern "C" void kernel_launch(void* const* d_in, const int* in_sizes, int n_in,
                              void* d_out, int out_size, void* d_ws, size_t ws_size,
                              hipStream_t stream) {
  const float* x        = (const float*)d_in[0];
  const int*   adj1_row = (const int*)d_in[1];
  const int*   adj1_col = (const int*)d_in[2];
  const float* adj1_val = (const float*)d_in[3];
  const int*   adj2_row = (const int*)d_in[4];
  const int*   adj2_col = (const int*)d_in[5];
  const float* adj2_val = (const float*)d_in[6];

  const int e1 = in_sizes[1];
  const int e2 = in_sizes[4];
  const int n  = in_sizes[0] / NFEAT;  // 100000
  const int nb = (n + SCAN_BLK - 1) / SCAN_BLK;  // 98

  float* out = (float*)d_out;

  // Workspace: p1[e1](8B), p2[e2](8B), off1[n+1], off2[n+1], cnt1[n], cnt2[n],
  //            bsum[2*nb]
  const size_t need = (size_t)(e1 + e2) * 8 + 2 * (size_t)(n + 1) * 4 +
                      2 * (size_t)n * 4 + 2 * (size_t)nb * 4;
  if (ws_size < need || nb > 256) {
    hipMemsetAsync(d_out, 0, (size_t)out_size * sizeof(float), stream);
    spmm_scatter_kernel<<<4096, 256, 0, stream>>>(adj1_row, adj1_col, adj1_val,
                                                  x, out, e1, 0);
    spmm_scatter_kernel<<<4096, 256, 0, stream>>>(adj2_row, adj2_col, adj2_val,
                                                  x, out, e2, NFEAT);
    return;
  }

  char* w = (char*)d_ws;
  long long* p1 = (long long*)w;  w += (size_t)e1 * 8;
  long long* p2 = (long long*)w;  w += (size_t)e2 * 8;
  int* off1 = (int*)w;            w += (size_t)(n + 1) * 4;
  int* off2 = (int*)w;            w += (size_t)(n + 1) * 4;
  int* cnt1 = (int*)w;            w += (size_t)n * 4;
  int* cnt2 = (int*)w;            w += (size_t)n * 4;
  int* bsum = (int*)w;

  hipMemsetAsync(cnt1, 0, 2 * (size_t)n * 4, stream);

  p1_hist<<<2048, 256, 0, stream>>>(adj1_row, e1, adj2_row, e2, cnt1, cnt2);
  p2a_blocksum<<<2 * nb, 256, 0, stream>>>(cnt1, cnt2, n, nb, bsum);
  p2b_scanb<<<1, 256, 0, stream>>>(bsum, nb, off1, off2, n);
  p2c_apply<<<2 * nb, 256, 0, stream>>>(cnt1, cnt2, n, nb, bsum, off1, off2);
  p3_scatter<<<2048, 256, 0, stream>>>(adj1_row, adj1_col, adj1_val, e1,
                                       adj2_row, adj2_col, adj2_val, e2,
                                       cnt1, cnt2, p1, p2);
  p4_gather<<<(2 * n * 64 + 255) / 256, 256, 0, stream>>>(off1, p1, off2, p2,
                                                          x, out, n);
}